// Round 1
// baseline (1155.721 us; speedup 1.0000x reference)
//
#include <hip/hip_runtime.h>

// Problem constants (fixed by the reference)
constexpr int B  = 8;
constexpr int C  = 1024;
constexpr int T  = 512;
constexpr int HW = 49;     // 7*7 spatial
constexpr int D  = 128;    // sim_dim == out_dim
constexpr int LW = 101;    // lookup window
constexpr int HALF = 50;   // (LW-1)/2

// ---------------------------------------------------------------------------
// Kernel 1: spatial mean. inputs [B,C,T,7,7] -> xm [B,C,T]
// UNCHANGED: measured at the HBM floor (~135 us for 822 MB read).
// ---------------------------------------------------------------------------
__global__ __launch_bounds__(256) void mean_kernel(const float* __restrict__ in,
                                                   float* __restrict__ xm) {
    __shared__ float lds[256 * HW];  // 12544 floats = 50176 B
    const int tid = threadIdx.x;
    const long long base = (long long)blockIdx.x * (256 * HW);

    const float4* in4 = (const float4*)(in + base);
    float4* lds4 = (float4*)lds;
#pragma unroll
    for (int k = 0; k < 12; ++k) {
        const int j = tid + k * 256;
        lds4[j] = in4[j];
    }
    if (tid < 64) lds4[3072 + tid] = in4[3072 + tid];
    __syncthreads();

    float s = 0.f;
#pragma unroll
    for (int j = 0; j < HW; ++j) s += lds[tid * HW + j];
    xm[(long long)blockIdx.x * 256 + tid] = s * (1.0f / 49.0f);
}

// ---------------------------------------------------------------------------
// Kernel 2: projection + bias + L2 normalize — v3: L2-direct, ZERO barriers.
// xm [B,C,T], pw [C,D], pb [D] -> y [B,T,D] normalized.
// Block: 8 t x 128 d (256 thr, per-thread 1t x 4d), grid (T/8, B) = 512
// blocks -> 2 blocks/CU, 2 waves/SIMD (2x the old occupancy, 0 of the old
// 32 barrier phases). pw (512 KB) and xm served by L2; pw b128 loads are
// broadcast-coalesced across the two half-wave t-groups. Norm reduction via
// __shfl_xor inside the contiguous 32-lane d-group (no LDS).
// blockIdx.x swizzle clusters adjacent t-tiles on one XCD so the stride-T
// xm broadcast loads share 64B lines in that XCD's L2.
// ---------------------------------------------------------------------------
constexpr int P_TT = 8;

__global__ __launch_bounds__(256) void proj_kernel(const float* __restrict__ xm,
                                                   const float* __restrict__ pw,
                                                   const float* __restrict__ pb,
                                                   float* __restrict__ y) {
    const int tid = threadIdx.x;
    const int tg  = tid >> 5;          // 0..7 -> local t row
    const int dg  = tid & 31;          // 0..31
    const int d0  = dg * 4;
    // XCD-cluster swizzle: gridDim.x = 64 (multiple of 8 XCDs) -> bijective.
    const int bxs = ((blockIdx.x & 7) << 3) | (blockIdx.x >> 3);
    const int t   = bxs * P_TT + tg;
    const int b   = blockIdx.y;

    const float* xmp = xm + (long long)b * C * T + t;  // stride T per c
    float4 acc = *(const float4*)&pb[d0];
#pragma unroll 8
    for (int c = 0; c < C; ++c) {
        const float  a = xmp[c * T];                        // 2 addrs/wave (broadcast)
        const float4 w = *(const float4*)&pw[c * D + d0];   // 512B coalesced, L2-hit
        acc.x += a * w.x; acc.y += a * w.y;
        acc.z += a * w.z; acc.w += a * w.w;
    }

    // L2 norm over d: butterfly within the contiguous 32-lane d-group
    float s = acc.x * acc.x + acc.y * acc.y + acc.z * acc.z + acc.w * acc.w;
#pragma unroll
    for (int m = 1; m <= 16; m <<= 1) s += __shfl_xor(s, m);
    const float sc = 1.0f / fmaxf(sqrtf(s), 1e-12f);

    *(float4*)&y[((long long)b * T + t) * D + d0] =
        make_float4(acc.x * sc, acc.y * sc, acc.z * sc, acc.w * sc);
}

// ---------------------------------------------------------------------------
// Kernel 3: banded cosine-sim + FC + ReLU — v2: L2-direct (no ybuf staging).
// y is 2 MB -> fully resident in each XCD's 4 MB L2; staging it to LDS was
// 55 KB + 2 barriers of pure overhead (common-mistake #7). Keep only the
// 3.2 KB band buffer + one barrier between the dot phase and the FC phase.
// band[b,t,w] = dot(y[b,t,:], y[b,t+w-50,:]) (zero outside [0,T))
// out[b,t,d]  = relu(sum_w band*fcw[w,d] + fcb[d])
// ---------------------------------------------------------------------------
constexpr int TT = 8;  // t-tile

__global__ __launch_bounds__(256) void band_fc_kernel(const float* __restrict__ y,
                                                      const float* __restrict__ fcw,
                                                      const float* __restrict__ fcb,
                                                      float* __restrict__ out) {
    __shared__ float band[TT][LW];     // 3232 B (only LDS in the kernel)

    const int tid = threadIdx.x;
    const int t0  = blockIdx.x * TT;
    const int b   = blockIdx.y;
    const float* yb = y + (long long)b * T * D;

    // band dots straight from L2: tl = j&7 fixed per thread (256 % 8 == 0),
    // so the a-row stays hot in L1 across this thread's w iterations.
    for (int j = tid; j < TT * LW; j += 256) {
        const int tl = j & 7;
        const int w  = j >> 3;
        const int s  = t0 + tl + w - HALF;
        float acc = 0.f;
        if (s >= 0 && s < T) {
            const float* a = yb + (t0 + tl) * D;
            const float* c = yb + s * D;
#pragma unroll 8
            for (int d = 0; d < D; d += 4) {
                const float4 av = *(const float4*)&a[d];
                const float4 cv = *(const float4*)&c[d];
                acc += av.x * cv.x + av.y * cv.y + av.z * cv.z + av.w * cv.w;
            }
        }
        band[tl][w] = acc;
    }
    __syncthreads();

    // FC + ReLU: tl = tid>>5, d0 = (tid&31)*4; fcw (51.7 KB) is L2-resident.
    const int tl = tid >> 5;
    const int d0 = (tid & 31) * 4;
    float4 acc = *(const float4*)&fcb[d0];
#pragma unroll 4
    for (int w = 0; w < LW; ++w) {
        const float  bv = band[tl][w];                         // LDS broadcast
        const float4 fw = *(const float4*)&fcw[w * D + d0];    // coalesced, L2-hit
        acc.x += bv * fw.x; acc.y += bv * fw.y;
        acc.z += bv * fw.z; acc.w += bv * fw.w;
    }
    acc.x = fmaxf(acc.x, 0.f); acc.y = fmaxf(acc.y, 0.f);
    acc.z = fmaxf(acc.z, 0.f); acc.w = fmaxf(acc.w, 0.f);
    *(float4*)&out[((long long)b * T + t0 + tl) * D + d0] = acc;
}

// ---------------------------------------------------------------------------
extern "C" void kernel_launch(void* const* d_in, const int* in_sizes, int n_in,
                              void* d_out, int out_size, void* d_ws, size_t ws_size,
                              hipStream_t stream) {
    const float* inputs = (const float*)d_in[0];  // [B,C,T,7,7]
    const float* proj_w = (const float*)d_in[1];  // [C,D]
    const float* proj_b = (const float*)d_in[2];  // [D]
    const float* fc_w   = (const float*)d_in[3];  // [LW,D]
    const float* fc_b   = (const float*)d_in[4];  // [D]
    float* out = (float*)d_out;                   // [B,T,D]

    float* xm = (float*)d_ws;                     // [B,C,T] (16 MB)
    float* y  = xm + (long long)B * C * T;        // [B,T,D] (2 MB)

    mean_kernel<<<16384, 256, 0, stream>>>(inputs, xm);
    proj_kernel<<<dim3(T / P_TT, B), 256, 0, stream>>>(xm, proj_w, proj_b, y);
    band_fc_kernel<<<dim3(T / TT, B), 256, 0, stream>>>(y, fc_w, fc_b, out);
}

// Round 2
// 1116.802 us; speedup vs baseline: 1.0348x; 1.0348x over previous
//
#include <hip/hip_runtime.h>

// Problem constants (fixed by the reference)
constexpr int B  = 8;
constexpr int C  = 1024;
constexpr int T  = 512;
constexpr int HW = 49;     // 7*7 spatial
constexpr int D  = 128;    // sim_dim == out_dim
constexpr int LW = 101;    // lookup window
constexpr int HALF = 50;   // (LW-1)/2

// ---------------------------------------------------------------------------
// Kernel 1: spatial mean. inputs [B,C,T,7,7] -> xm [B,C,T]
// UNCHANGED: measured at the HBM floor (~135 us for 822 MB read).
// ---------------------------------------------------------------------------
__global__ __launch_bounds__(256) void mean_kernel(const float* __restrict__ in,
                                                   float* __restrict__ xm) {
    __shared__ float lds[256 * HW];  // 12544 floats = 50176 B
    const int tid = threadIdx.x;
    const long long base = (long long)blockIdx.x * (256 * HW);

    const float4* in4 = (const float4*)(in + base);
    float4* lds4 = (float4*)lds;
#pragma unroll
    for (int k = 0; k < 12; ++k) {
        const int j = tid + k * 256;
        lds4[j] = in4[j];
    }
    if (tid < 64) lds4[3072 + tid] = in4[3072 + tid];
    __syncthreads();

    float s = 0.f;
#pragma unroll
    for (int j = 0; j < HW; ++j) s += lds[tid * HW + j];
    xm[(long long)blockIdx.x * 256 + tid] = s * (1.0f / 49.0f);
}

// ---------------------------------------------------------------------------
// Kernel 2: projection + bias + L2 normalize — v4.
// xm [B,C,T], pw [C,D], pb [D] -> y [B,T,D] normalized.
// Block: 16 t x 128 d (256 thr, per-thread 2t x 4d), grid (T/16, B) = 256
// blocks (1/CU, full chip). Stage the ENTIRE xm slab [C][16] = 64 KB once:
//  - global reads are full 64B lines (4 lanes x float4 per c-row);
//  - LDS write address = 16B * lane-linear -> perfectly conflict-free;
//  - ONE barrier total (v2 had 32).
// Compute: per c, one ds_read_b64 (tA,tB adjacent) + one L2-direct float4 of
// pw reused for both t rows (halves v3's per-wave pw L1 traffic), 8 FMA.
// Norm via __shfl_xor butterfly in the 32-lane d-group — no LDS, no barrier.
// ---------------------------------------------------------------------------
constexpr int P_TT = 16;

__global__ __launch_bounds__(256) void proj_kernel(const float* __restrict__ xm,
                                                   const float* __restrict__ pw,
                                                   const float* __restrict__ pb,
                                                   float* __restrict__ y) {
    __shared__ float xmt[C * P_TT];   // 65536 B exactly

    const int tid = threadIdx.x;
    const int t0  = blockIdx.x * P_TT;
    const int b   = blockIdx.y;

    // stage xm slab: 4096 float4, 16 per thread; LDS side is lane-linear.
#pragma unroll
    for (int k = 0; k < 16; ++k) {
        const int j  = tid + k * 256;     // 0..4095
        const int c  = j >> 2;
        const int t4 = (j & 3) * 4;
        const float4 v = *(const float4*)&xm[((long long)b * C + c) * T + t0 + t4];
        *(float4*)&xmt[c * P_TT + t4] = v;
    }
    __syncthreads();

    const int tg = tid >> 5;          // 0..7
    const int dg = tid & 31;          // 0..31
    const int d0 = dg * 4;
    const int tA = tg * 2;            // tB = tA + 1

    float4 accA = *(const float4*)&pb[d0];
    float4 accB = accA;

#pragma unroll 8
    for (int c = 0; c < C; ++c) {
        const float2 a = *(const float2*)&xmt[c * P_TT + tA];  // b64 broadcast
        const float4 w = *(const float4*)&pw[c * D + d0];      // L2-hit, reused x2
        accA.x += a.x * w.x; accA.y += a.x * w.y;
        accA.z += a.x * w.z; accA.w += a.x * w.w;
        accB.x += a.y * w.x; accB.y += a.y * w.y;
        accB.z += a.y * w.z; accB.w += a.y * w.w;
    }

    // L2 norm over d: butterfly within the contiguous 32-lane d-group
    float sA = accA.x*accA.x + accA.y*accA.y + accA.z*accA.z + accA.w*accA.w;
    float sB = accB.x*accB.x + accB.y*accB.y + accB.z*accB.z + accB.w*accB.w;
#pragma unroll
    for (int m = 1; m <= 16; m <<= 1) {
        sA += __shfl_xor(sA, m);
        sB += __shfl_xor(sB, m);
    }
    const float scA = 1.0f / fmaxf(sqrtf(sA), 1e-12f);
    const float scB = 1.0f / fmaxf(sqrtf(sB), 1e-12f);

    float* yoA = y + ((long long)b * T + t0 + tA) * D + d0;
    *(float4*)yoA = make_float4(accA.x * scA, accA.y * scA, accA.z * scA, accA.w * scA);
    *(float4*)(yoA + D) = make_float4(accB.x * scB, accB.y * scB, accB.z * scB, accB.w * scB);
}

// ---------------------------------------------------------------------------
// Kernel 3: banded cosine-sim + FC + ReLU — round-0 LDS-staged version
// (verbatim revert: the L2-direct variant fragmented vmem 16-way and
// regressed). y rows are reused ~101x each -> LDS staging pays.
// ---------------------------------------------------------------------------
constexpr int TT    = 8;              // t-tile
constexpr int ROWS  = TT + 2 * HALF;  // 108
constexpr int YPAD  = 132;            // padded row stride (floats)

__global__ __launch_bounds__(256) void band_fc_kernel(const float* __restrict__ y,
                                                      const float* __restrict__ fcw,
                                                      const float* __restrict__ fcb,
                                                      float* __restrict__ out) {
    __shared__ float ybuf[ROWS][YPAD];     // 57024 B
    __shared__ float band[TT][LW];         // 3232 B

    const int tid = threadIdx.x;
    const int t0  = blockIdx.x * TT;
    const int b   = blockIdx.y;

    // stage y rows (zero-fill out of range): 108*32 = 3456 float4
    for (int j = tid; j < ROWS * 32; j += 256) {
        const int row = j >> 5;
        const int dd  = (j & 31) * 4;
        const int s   = t0 - HALF + row;
        float4 v = make_float4(0.f, 0.f, 0.f, 0.f);
        if (s >= 0 && s < T) v = *(const float4*)&y[((long long)b * T + s) * D + dd];
        *(float4*)&ybuf[row][dd] = v;
    }
    __syncthreads();

    // band dots: 8*101 = 808; tl = j&7 fixed per thread, w = j>>3
    for (int j = tid; j < TT * LW; j += 256) {
        const int tl = j & 7;
        const int w  = j >> 3;
        const float* a = ybuf[tl + HALF];
        const float* c = ybuf[tl + w];
        float s = 0.f;
#pragma unroll
        for (int d = 0; d < D; d += 4) {
            const float4 av = *(const float4*)&a[d];
            const float4 cv = *(const float4*)&c[d];
            s += av.x * cv.x + av.y * cv.y + av.z * cv.z + av.w * cv.w;
        }
        band[tl][w] = s;
    }
    __syncthreads();

    // FC + ReLU: tl = tid>>5, d0 = (tid&31)*4
    const int tl = tid >> 5;
    const int d0 = (tid & 31) * 4;
    float4 acc = *(const float4*)&fcb[d0];
    for (int w = 0; w < LW; ++w) {
        const float  bv = band[tl][w];                        // LDS broadcast
        const float4 fw = *(const float4*)&fcw[(long long)w * D + d0];  // L2-resident
        acc.x += bv * fw.x; acc.y += bv * fw.y;
        acc.z += bv * fw.z; acc.w += bv * fw.w;
    }
    acc.x = fmaxf(acc.x, 0.f); acc.y = fmaxf(acc.y, 0.f);
    acc.z = fmaxf(acc.z, 0.f); acc.w = fmaxf(acc.w, 0.f);
    *(float4*)&out[((long long)b * T + t0 + tl) * D + d0] = acc;
}

// ---------------------------------------------------------------------------
extern "C" void kernel_launch(void* const* d_in, const int* in_sizes, int n_in,
                              void* d_out, int out_size, void* d_ws, size_t ws_size,
                              hipStream_t stream) {
    const float* inputs = (const float*)d_in[0];  // [B,C,T,7,7]
    const float* proj_w = (const float*)d_in[1];  // [C,D]
    const float* proj_b = (const float*)d_in[2];  // [D]
    const float* fc_w   = (const float*)d_in[3];  // [LW,D]
    const float* fc_b   = (const float*)d_in[4];  // [D]
    float* out = (float*)d_out;                   // [B,T,D]

    float* xm = (float*)d_ws;                     // [B,C,T] (16 MB)
    float* y  = xm + (long long)B * C * T;        // [B,T,D] (2 MB)

    mean_kernel<<<16384, 256, 0, stream>>>(inputs, xm);
    proj_kernel<<<dim3(T / P_TT, B), 256, 0, stream>>>(xm, proj_w, proj_b, y);
    band_fc_kernel<<<dim3(T / TT, B), 256, 0, stream>>>(y, fc_w, fc_b, out);
}

// Round 3
// 1070.166 us; speedup vs baseline: 1.0799x; 1.0436x over previous
//
#include <hip/hip_runtime.h>

// Problem constants (fixed by the reference)
constexpr int B  = 8;
constexpr int C  = 1024;
constexpr int T  = 512;
constexpr int HW = 49;     // 7*7 spatial
constexpr int D  = 128;    // sim_dim == out_dim
constexpr int LW = 101;    // lookup window
constexpr int HALF = 50;   // (LW-1)/2

// ---------------------------------------------------------------------------
// Kernel 1: spatial mean. inputs [B,C,T,7,7] -> xm [B,C,T]
// UNCHANGED: measured at the HBM floor (~135 us for 822 MB read).
// ---------------------------------------------------------------------------
__global__ __launch_bounds__(256) void mean_kernel(const float* __restrict__ in,
                                                   float* __restrict__ xm) {
    __shared__ float lds[256 * HW];  // 12544 floats = 50176 B
    const int tid = threadIdx.x;
    const long long base = (long long)blockIdx.x * (256 * HW);

    const float4* in4 = (const float4*)(in + base);
    float4* lds4 = (float4*)lds;
#pragma unroll
    for (int k = 0; k < 12; ++k) {
        const int j = tid + k * 256;
        lds4[j] = in4[j];
    }
    if (tid < 64) lds4[3072 + tid] = in4[3072 + tid];
    __syncthreads();

    float s = 0.f;
#pragma unroll
    for (int j = 0; j < HW; ++j) s += lds[tid * HW + j];
    xm[(long long)blockIdx.x * 256 + tid] = s * (1.0f / 49.0f);
}

// ---------------------------------------------------------------------------
// Kernel 2a: projection partials — C-split v6.
// Split C into 8 chunks of 128; grid (T/32, B, 8) = 1024 blocks -> 4/CU.
// Tile 32t x 128d, per-thread 4t x 4d: per cc, ONE b128 of xmt (2-addr
// broadcast) + ONE b128 of pwt feed 16 FMA (LDS cyc/FMA ~1.4 vs 2.25 in v2),
// and 4 blocks/CU overlap the barrier drains that v2 (1 block/CU) exposed.
// Partials go to 8 separate buffers (deterministic, no atomics).
// ---------------------------------------------------------------------------
constexpr int P6_TT  = 32;            // t per block
constexpr int P6_CC  = 64;            // c per phase
constexpr int CSPLIT = 8;
constexpr int CCHUNK = C / CSPLIT;    // 128 -> 2 phases per block

__global__ __launch_bounds__(256) void proj_part_kernel(const float* __restrict__ xm,
                                                        const float* __restrict__ pw,
                                                        float* __restrict__ ypart) {
    __shared__ float xmt[P6_CC][P6_TT];   // 8 KB
    __shared__ float pwt[P6_CC][D];       // 32 KB  (40 KB total -> up to 4/CU)

    const int tid = threadIdx.x;
    const int t0  = blockIdx.x * P6_TT;   // gridDim.x = 16
    const int b   = blockIdx.y;
    const int cb  = blockIdx.z * CCHUNK;

    const int tg = tid >> 5;              // 0..7
    const int dg = tid & 31;              // 0..31
    const int d0 = dg * 4;
    const int tA = tg * 4;

    float4 acc0 = make_float4(0.f, 0.f, 0.f, 0.f);
    float4 acc1 = acc0, acc2 = acc0, acc3 = acc0;

    for (int ph = 0; ph < CCHUNK; ph += P6_CC) {
        const int c0 = cb + ph;
        __syncthreads();
        // stage xmt: 64 cc x 32 t = 512 float4 (2/thread); global rows of
        // 128B contiguous per c; LDS writes dense b128 (conflict-free).
#pragma unroll
        for (int k = 0; k < 2; ++k) {
            const int j  = tid + k * 256;
            const int cc = j >> 3;
            const int t4 = (j & 7) * 4;
            *(float4*)&xmt[cc][t4] =
                *(const float4*)&xm[((long long)b * C + c0 + cc) * T + t0 + t4];
        }
        // stage pwt: 64 cc x 128 d = 2048 float4 (8/thread, coalesced).
#pragma unroll
        for (int k = 0; k < 8; ++k) {
            const int j  = tid + k * 256;
            const int cc = j >> 5;
            const int dd = (j & 31) * 4;
            *(float4*)&pwt[cc][dd] = *(const float4*)&pw[(long long)(c0 + cc) * D + dd];
        }
        __syncthreads();
#pragma unroll 8
        for (int cc = 0; cc < P6_CC; ++cc) {
            const float4 a = *(const float4*)&xmt[cc][tA];   // 2 addrs/wave
            const float4 w = *(const float4*)&pwt[cc][d0];   // dense b128
            acc0.x += a.x * w.x; acc0.y += a.x * w.y; acc0.z += a.x * w.z; acc0.w += a.x * w.w;
            acc1.x += a.y * w.x; acc1.y += a.y * w.y; acc1.z += a.y * w.z; acc1.w += a.y * w.w;
            acc2.x += a.z * w.x; acc2.y += a.z * w.y; acc2.z += a.z * w.z; acc2.w += a.z * w.w;
            acc3.x += a.w * w.x; acc3.y += a.w * w.y; acc3.z += a.w * w.z; acc3.w += a.w * w.w;
        }
    }

    float* yp = ypart + (long long)blockIdx.z * (B * T * D)
                      + ((long long)b * T + t0 + tA) * D + d0;
    *(float4*)yp            = acc0;
    *(float4*)(yp + D)      = acc1;
    *(float4*)(yp + 2 * D)  = acc2;
    *(float4*)(yp + 3 * D)  = acc3;
}

// ---------------------------------------------------------------------------
// Kernel 2b: sum partials + bias + L2 normalize -> y [B,T,D].
// 4096 rows; block = 8 rows x 32 lanes (4d each); norm via __shfl_xor.
// ---------------------------------------------------------------------------
__global__ __launch_bounds__(256) void norm_kernel(const float* __restrict__ ypart,
                                                   const float* __restrict__ pb,
                                                   float* __restrict__ y) {
    const int tid = threadIdx.x;
    const int row = blockIdx.x * 8 + (tid >> 5);   // b*T + t
    const int d0  = (tid & 31) * 4;
    const long long stride = (long long)B * T * D;

    float4 acc = *(const float4*)&pb[d0];
#pragma unroll
    for (int cz = 0; cz < CSPLIT; ++cz) {
        const float4 v = *(const float4*)&ypart[cz * stride + (long long)row * D + d0];
        acc.x += v.x; acc.y += v.y; acc.z += v.z; acc.w += v.w;
    }

    float s = acc.x * acc.x + acc.y * acc.y + acc.z * acc.z + acc.w * acc.w;
#pragma unroll
    for (int m = 1; m <= 16; m <<= 1) s += __shfl_xor(s, m);
    const float sc = 1.0f / fmaxf(sqrtf(s), 1e-12f);

    *(float4*)&y[(long long)row * D + d0] =
        make_float4(acc.x * sc, acc.y * sc, acc.z * sc, acc.w * sc);
}

// ---------------------------------------------------------------------------
// Kernel 3: banded cosine-sim + FC + ReLU — round-0 LDS-staged version
// (verbatim: known best; L2-direct variant regressed +39 us).
// ---------------------------------------------------------------------------
constexpr int TT    = 8;              // t-tile
constexpr int ROWS  = TT + 2 * HALF;  // 108
constexpr int YPAD  = 132;            // padded row stride (floats)

__global__ __launch_bounds__(256) void band_fc_kernel(const float* __restrict__ y,
                                                      const float* __restrict__ fcw,
                                                      const float* __restrict__ fcb,
                                                      float* __restrict__ out) {
    __shared__ float ybuf[ROWS][YPAD];     // 57024 B
    __shared__ float band[TT][LW];         // 3232 B

    const int tid = threadIdx.x;
    const int t0  = blockIdx.x * TT;
    const int b   = blockIdx.y;

    // stage y rows (zero-fill out of range): 108*32 = 3456 float4
    for (int j = tid; j < ROWS * 32; j += 256) {
        const int row = j >> 5;
        const int dd  = (j & 31) * 4;
        const int s   = t0 - HALF + row;
        float4 v = make_float4(0.f, 0.f, 0.f, 0.f);
        if (s >= 0 && s < T) v = *(const float4*)&y[((long long)b * T + s) * D + dd];
        *(float4*)&ybuf[row][dd] = v;
    }
    __syncthreads();

    // band dots: 8*101 = 808; tl = j&7 fixed per thread, w = j>>3
    for (int j = tid; j < TT * LW; j += 256) {
        const int tl = j & 7;
        const int w  = j >> 3;
        const float* a = ybuf[tl + HALF];
        const float* c = ybuf[tl + w];
        float s = 0.f;
#pragma unroll
        for (int d = 0; d < D; d += 4) {
            const float4 av = *(const float4*)&a[d];
            const float4 cv = *(const float4*)&c[d];
            s += av.x * cv.x + av.y * cv.y + av.z * cv.z + av.w * cv.w;
        }
        band[tl][w] = s;
    }
    __syncthreads();

    // FC + ReLU: tl = tid>>5, d0 = (tid&31)*4
    const int tl = tid >> 5;
    const int d0 = (tid & 31) * 4;
    float4 acc = *(const float4*)&fcb[d0];
    for (int w = 0; w < LW; ++w) {
        const float  bv = band[tl][w];                        // LDS broadcast
        const float4 fw = *(const float4*)&fcw[(long long)w * D + d0];  // L2-resident
        acc.x += bv * fw.x; acc.y += bv * fw.y;
        acc.z += bv * fw.z; acc.w += bv * fw.w;
    }
    acc.x = fmaxf(acc.x, 0.f); acc.y = fmaxf(acc.y, 0.f);
    acc.z = fmaxf(acc.z, 0.f); acc.w = fmaxf(acc.w, 0.f);
    *(float4*)&out[((long long)b * T + t0 + tl) * D + d0] = acc;
}

// ---------------------------------------------------------------------------
extern "C" void kernel_launch(void* const* d_in, const int* in_sizes, int n_in,
                              void* d_out, int out_size, void* d_ws, size_t ws_size,
                              hipStream_t stream) {
    const float* inputs = (const float*)d_in[0];  // [B,C,T,7,7]
    const float* proj_w = (const float*)d_in[1];  // [C,D]
    const float* proj_b = (const float*)d_in[2];  // [D]
    const float* fc_w   = (const float*)d_in[3];  // [LW,D]
    const float* fc_b   = (const float*)d_in[4];  // [D]
    float* out = (float*)d_out;                   // [B,T,D]

    float* xm    = (float*)d_ws;                         // [B,C,T]    (16 MB)
    float* y     = xm + (long long)B * C * T;            // [B,T,D]    ( 2 MB)
    float* ypart = y + (long long)B * T * D;             // [8][B,T,D] (16 MB)

    mean_kernel<<<16384, 256, 0, stream>>>(inputs, xm);
    proj_part_kernel<<<dim3(T / P6_TT, B, CSPLIT), 256, 0, stream>>>(xm, proj_w, ypart);
    norm_kernel<<<(B * T) / 8, 256, 0, stream>>>(ypart, proj_b, y);
    band_fc_kernel<<<dim3(T / TT, B), 256, 0, stream>>>(y, fc_w, fc_b, out);
}